// Round 7
// baseline (60.784 us; speedup 1.0000x reference)
//
#include <hip/hip_runtime.h>

// Problem constants
#define BB 32
#define KK 5
#define TT 20
#define VV 9488
#define HH 1024
#define NSPLIT 16
#define CHUNK (VV / NSPLIT)   // 593 exactly

// Output layout (floats), concatenated in return order:
// out0 beam_seq          : [0,        3360)
// out1 beam_seq_logprobs : [3360,     31883040)
// out2 beam_logprobs_sum : [31883040, 31883200)
// out3 new_state         : [31883200, 32210880)
#define OFF1 3360
#define OFF2 31883040
#define OFF3 31883200

#define N1F4 7969920          // 3360 rows * 2372 f4 per row
#define NSF4 81920            // 320 rows * 256 f4 per row
#define TOTF4 (N1F4 + NSF4)   // 8051840

#define CPBLK 2048            // copy-kernel blocks (compile-time for stride math)

typedef float f4 __attribute__((ext_vector_type(4)));
typedef unsigned long long u64;

__device__ __forceinline__ bool better(float av, int ai, float bv, int bi) {
    // total order: value descending, then index ascending (jax top_k tie-break)
    return (av > bv) || (av == bv && ai < bi);
}

// ---------------- Phase 1: per-(batch, v-slice) partial top-5 ----------------
// 512 blocks x 256. Branchy insert: guard is ~1 op/candidate, rarely taken.
__global__ __launch_bounds__(256) void topk_part_kernel(
    const float* __restrict__ logprobs,      // (B*K, V)
    const float* __restrict__ sums,          // (B, K)
    float* __restrict__ pv,                  // (B*NSPLIT, 5)
    int*   __restrict__ pi)
{
    const int b    = blockIdx.x / NSPLIT;
    const int part = blockIdx.x % NSPLIT;
    const int tid  = threadIdx.x;
    const int v0   = part * CHUNK;

    float tv[5]; int ti[5];
#pragma unroll
    for (int j = 0; j < 5; ++j) { tv[j] = -INFINITY; ti[j] = 0x7FFFFF00 + j; }

    for (int k = 0; k < KK; ++k) {
        const float s = sums[b * KK + k];
        const float* lp = logprobs + (size_t)(b * KK + k) * VV;
        for (int v = v0 + tid; v < v0 + CHUNK; v += 256) {
            const float val = s + lp[v];
            const int idx = k * VV + v;
            if (better(val, idx, tv[4], ti[4])) {
                int pos = 4;
#pragma unroll
                for (int j = 3; j >= 0; --j)
                    if (better(val, idx, tv[j], ti[j])) pos = j;
#pragma unroll
                for (int j = 4; j > 0; --j) {
                    if (j > pos) { tv[j] = tv[j-1]; ti[j] = ti[j-1]; }
                }
                tv[pos] = val; ti[pos] = idx;
            }
        }
    }

    __shared__ float sv[256 * 5];
    __shared__ int   si[256 * 5];

    for (int stride = 128; stride >= 1; stride >>= 1) {
        if (tid >= stride && tid < 2 * stride) {
#pragma unroll
            for (int j = 0; j < 5; ++j) { sv[tid*5+j] = tv[j]; si[tid*5+j] = ti[j]; }
        }
        __syncthreads();
        if (tid < stride) {
            float bv[5]; int bi[5];
#pragma unroll
            for (int j = 0; j < 5; ++j) { bv[j] = sv[(tid+stride)*5+j]; bi[j] = si[(tid+stride)*5+j]; }
            float ov[5]; int oi[5];
            int ia = 0, ib = 0;
#pragma unroll
            for (int n = 0; n < 5; ++n) {
                if (better(tv[ia], ti[ia], bv[ib], bi[ib])) { ov[n] = tv[ia]; oi[n] = ti[ia]; ++ia; }
                else                                        { ov[n] = bv[ib]; oi[n] = bi[ib]; ++ib; }
            }
#pragma unroll
            for (int j = 0; j < 5; ++j) { tv[j] = ov[j]; ti[j] = oi[j]; }
        }
        __syncthreads();
    }

    if (tid == 0) {
#pragma unroll
        for (int j = 0; j < 5; ++j) {
            pv[(size_t)blockIdx.x * 5 + j] = tv[j];
            pi[(size_t)blockIdx.x * 5 + j] = ti[j];
        }
    }
}

// Merge two descending sorted 5-lists, keep top-5. Static indices only.
__device__ __forceinline__ void merge_sorted5(float av[5], int ai[5],
                                              const float bv[5], const int bi[5]) {
    float ov[5]; int oi[5];
#pragma unroll
    for (int n = 0; n < 5; ++n) {
        float mv = 0.f; int mi = 0;
#pragma unroll
        for (int i = 0; i <= n; ++i) {
            const int j = n - i;
            float cv; int ci;
            if (better(av[i], ai[i], bv[j], bi[j])) { cv = av[i]; ci = ai[i]; }
            else                                    { cv = bv[j]; ci = bi[j]; }
            if (i == 0 || better(mv, mi, cv, ci)) { mv = cv; mi = ci; }  // keep worst
        }
        ov[n] = mv; oi[n] = mi;
    }
#pragma unroll
    for (int n = 0; n < 5; ++n) { av[n] = ov[n]; ai[n] = oi[n]; }
}

// ---------------- Phase 2: final merge + small outputs + src-address tables ---
__global__ __launch_bounds__(64) void merge_kernel(
    const float* __restrict__ pv,
    const int*   __restrict__ pi,
    const float* __restrict__ logprobs,      // (B*K, V)
    const int*   __restrict__ beam_seq_in,   // (B, K, T)
    const float* __restrict__ bslp_in,       // (B, K, T, V)
    const float* __restrict__ state_in,      // (2, B*K, H)
    u64* __restrict__ srcrow,                // [3360] src addr per out1 row
    u64* __restrict__ srcst,                 // [320]  src addr per state row
    float* __restrict__ out)
{
    const int b   = blockIdx.x;
    const int tid = threadIdx.x;

    float tv[5]; int ti[5];
    if (tid < NSPLIT) {
        const size_t base = ((size_t)b * NSPLIT + tid) * 5;
#pragma unroll
        for (int j = 0; j < 5; ++j) { tv[j] = pv[base + j]; ti[j] = pi[base + j]; }
    } else {
#pragma unroll
        for (int j = 0; j < 5; ++j) { tv[j] = -INFINITY; ti[j] = 0x7FFFFF00 + j; }
    }

    // shuffle-allreduce within the first 16 lanes, then broadcast lane 0
#pragma unroll
    for (int st = 1; st <= 8; st <<= 1) {
        float bv[5]; int bi[5];
#pragma unroll
        for (int j = 0; j < 5; ++j) {
            bv[j] = __shfl_xor(tv[j], st);
            bi[j] = __shfl_xor(ti[j], st);
        }
        merge_sorted5(tv, ti, bv, bi);
    }
#pragma unroll
    for (int j = 0; j < 5; ++j) {
        tv[j] = __shfl(tv[j], 0);
        ti[j] = __shfl(ti[j], 0);
    }
    // every lane now holds the final top-5 for batch b
    int beam[5], sel[5];
#pragma unroll
    for (int j = 0; j < 5; ++j) { beam[j] = ti[j] / VV; sel[j] = ti[j] - beam[j] * VV; }

    // out1 source-row table + beam_seq output (105 rows per batch)
    for (int rr = tid; rr < KK * (TT + 1); rr += 64) {
        const int k = rr / (TT + 1), t = rr % (TT + 1);
        int bm = 0, sl = 0;
#pragma unroll
        for (int j = 0; j < 5; ++j) if (k == j) { bm = beam[j]; sl = sel[j]; }
        const float* src = (t < TT)
            ? bslp_in  + ((size_t)((b * KK + bm) * TT + t)) * VV
            : logprobs + (size_t)(b * KK + bm) * VV;
        srcrow[b * KK * (TT + 1) + rr] = (u64)(uintptr_t)src;
        const int val = (t < TT) ? beam_seq_in[(size_t)(b * KK + bm) * TT + t] : sl;
        out[(size_t)b * KK * (TT + 1) + rr] = (float)val;
    }

    // state source-row table (2 x 5 rows per batch)
    if (tid < 10) {
        const int s = tid / 5, k = tid % 5;
        int bm = 0;
#pragma unroll
        for (int j = 0; j < 5; ++j) if (k == j) bm = beam[j];
        srcst[s * (BB * KK) + b * KK + k] =
            (u64)(uintptr_t)(state_in + ((size_t)s * (BB * KK) + b * KK + bm) * HH);
    }

    // beam_logprobs_sum output
    if (tid == 0) {
#pragma unroll
        for (int j = 0; j < 5; ++j) out[OFF2 + b * KK + j] = tv[j];
    }
}

// ---------------- Phase 3: flat grid-stride float4 copy, 4-deep MLP ----------
__device__ __forceinline__ f4 load_src(const u64* __restrict__ srcrow,
                                       const u64* __restrict__ srcst, int idx) {
    if (idx < N1F4) {
        const unsigned row = (unsigned)idx / 2372u;
        const unsigned col = (unsigned)idx - row * 2372u;
        const f4* __restrict__ s = (const f4*)(uintptr_t)srcrow[row];
        return s[col];
    } else {
        const int j = idx - N1F4;
        const f4* __restrict__ s = (const f4*)(uintptr_t)srcst[j >> 8];
        return s[j & 255];
    }
}

__global__ __launch_bounds__(256) void copy_kernel(
    const u64* __restrict__ srcrow,
    const u64* __restrict__ srcst,
    float* __restrict__ out)
{
    f4* __restrict__ dst1 = (f4*)(out + OFF1);   // contiguous through dst3
    const int stride = CPBLK * 256;              // compile-time constant
    const int start  = blockIdx.x * 256 + threadIdx.x;

    // 4-deep static unroll: 4 independent gather chains in flight per thread
    for (int base = start; base < TOTF4; base += 4 * stride) {
        f4 va[4];
#pragma unroll
        for (int m = 0; m < 4; ++m) {
            const int id = base + m * stride;
            if (id < TOTF4) va[m] = load_src(srcrow, srcst, id);
        }
#pragma unroll
        for (int m = 0; m < 4; ++m) {
            const int id = base + m * stride;
            if (id < TOTF4) dst1[id] = va[m];    // dst1..dst3 contiguous in out
        }
    }
}

extern "C" void kernel_launch(void* const* d_in, const int* in_sizes, int n_in,
                              void* d_out, int out_size, void* d_ws, size_t ws_size,
                              hipStream_t stream) {
    const float* logprobs = (const float*)d_in[0];
    const int*   beam_seq = (const int*)  d_in[1];
    const float* bslp     = (const float*)d_in[2];
    const float* sums     = (const float*)d_in[3];
    const float* state    = (const float*)d_in[4];

    // ws layout: 8B-aligned tables first, then pv/pi
    u64*   srcrow = (u64*)d_ws;                       // 3360 entries
    u64*   srcst  = srcrow + BB * KK * (TT + 1);      // 320 entries
    float* pv     = (float*)(srcst + 2 * BB * KK);    // 2560 floats
    int*   pi     = (int*)(pv + BB * NSPLIT * 5);     // 2560 ints
    float* out    = (float*)d_out;

    topk_part_kernel<<<BB * NSPLIT, 256, 0, stream>>>(logprobs, sums, pv, pi);
    merge_kernel<<<BB, 64, 0, stream>>>(pv, pi, logprobs, beam_seq, bslp, state,
                                        srcrow, srcst, out);
    copy_kernel<<<CPBLK, 256, 0, stream>>>(srcrow, srcst, out);
}

// Round 8
// 58.542 us; speedup vs baseline: 1.0383x; 1.0383x over previous
//
#include <hip/hip_runtime.h>

// Problem constants
#define BB 32
#define KK 5
#define TT 20
#define VV 9488
#define HH 1024
#define NSPLIT 16
#define CHUNK (VV / NSPLIT)   // 593 exactly

// Output layout (floats), concatenated in return order:
// out0 beam_seq          : [0,        3360)
// out1 beam_seq_logprobs : [3360,     31883040)
// out2 beam_logprobs_sum : [31883040, 31883200)   <-- sits BETWEEN out1 and out3!
// out3 new_state         : [31883200, 32210880)
#define OFF1 3360
#define OFF2 31883040
#define OFF3 31883200

#define N1F4 7969920          // 3360 rows * 2372 f4 per row
#define NSF4 81920            // 320 rows * 256 f4 per row
#define TOTF4 (N1F4 + NSF4)   // 8051840

typedef float f4 __attribute__((ext_vector_type(4)));
typedef unsigned long long u64;

__device__ __forceinline__ bool better(float av, int ai, float bv, int bi) {
    // total order: value descending, then index ascending (jax top_k tie-break)
    return (av > bv) || (av == bv && ai < bi);
}

// ---------------- Phase 1: per-(batch, v-slice) partial top-5 ----------------
// 512 blocks x 256. Branchy insert: guard is ~1 op/candidate, rarely taken.
__global__ __launch_bounds__(256) void topk_part_kernel(
    const float* __restrict__ logprobs,      // (B*K, V)
    const float* __restrict__ sums,          // (B, K)
    float* __restrict__ pv,                  // (B*NSPLIT, 5)
    int*   __restrict__ pi)
{
    const int b    = blockIdx.x / NSPLIT;
    const int part = blockIdx.x % NSPLIT;
    const int tid  = threadIdx.x;
    const int v0   = part * CHUNK;

    float tv[5]; int ti[5];
#pragma unroll
    for (int j = 0; j < 5; ++j) { tv[j] = -INFINITY; ti[j] = 0x7FFFFF00 + j; }

    for (int k = 0; k < KK; ++k) {
        const float s = sums[b * KK + k];
        const float* lp = logprobs + (size_t)(b * KK + k) * VV;
        for (int v = v0 + tid; v < v0 + CHUNK; v += 256) {
            const float val = s + lp[v];
            const int idx = k * VV + v;
            if (better(val, idx, tv[4], ti[4])) {
                int pos = 4;
#pragma unroll
                for (int j = 3; j >= 0; --j)
                    if (better(val, idx, tv[j], ti[j])) pos = j;
#pragma unroll
                for (int j = 4; j > 0; --j) {
                    if (j > pos) { tv[j] = tv[j-1]; ti[j] = ti[j-1]; }
                }
                tv[pos] = val; ti[pos] = idx;
            }
        }
    }

    __shared__ float sv[256 * 5];
    __shared__ int   si[256 * 5];

    for (int stride = 128; stride >= 1; stride >>= 1) {
        if (tid >= stride && tid < 2 * stride) {
#pragma unroll
            for (int j = 0; j < 5; ++j) { sv[tid*5+j] = tv[j]; si[tid*5+j] = ti[j]; }
        }
        __syncthreads();
        if (tid < stride) {
            float bv[5]; int bi[5];
#pragma unroll
            for (int j = 0; j < 5; ++j) { bv[j] = sv[(tid+stride)*5+j]; bi[j] = si[(tid+stride)*5+j]; }
            float ov[5]; int oi[5];
            int ia = 0, ib = 0;
#pragma unroll
            for (int n = 0; n < 5; ++n) {
                if (better(tv[ia], ti[ia], bv[ib], bi[ib])) { ov[n] = tv[ia]; oi[n] = ti[ia]; ++ia; }
                else                                        { ov[n] = bv[ib]; oi[n] = bi[ib]; ++ib; }
            }
#pragma unroll
            for (int j = 0; j < 5; ++j) { tv[j] = ov[j]; ti[j] = oi[j]; }
        }
        __syncthreads();
    }

    if (tid == 0) {
#pragma unroll
        for (int j = 0; j < 5; ++j) {
            pv[(size_t)blockIdx.x * 5 + j] = tv[j];
            pi[(size_t)blockIdx.x * 5 + j] = ti[j];
        }
    }
}

// Merge two descending sorted 5-lists, keep top-5. Static indices only.
__device__ __forceinline__ void merge_sorted5(float av[5], int ai[5],
                                              const float bv[5], const int bi[5]) {
    float ov[5]; int oi[5];
#pragma unroll
    for (int n = 0; n < 5; ++n) {
        float mv = 0.f; int mi = 0;
#pragma unroll
        for (int i = 0; i <= n; ++i) {
            const int j = n - i;
            float cv; int ci;
            if (better(av[i], ai[i], bv[j], bi[j])) { cv = av[i]; ci = ai[i]; }
            else                                    { cv = bv[j]; ci = bi[j]; }
            if (i == 0 || better(mv, mi, cv, ci)) { mv = cv; mi = ci; }  // keep worst
        }
        ov[n] = mv; oi[n] = mi;
    }
#pragma unroll
    for (int n = 0; n < 5; ++n) { av[n] = ov[n]; ai[n] = oi[n]; }
}

// ---------------- Phase 2: final merge + small outputs + src-address tables ---
__global__ __launch_bounds__(64) void merge_kernel(
    const float* __restrict__ pv,
    const int*   __restrict__ pi,
    const float* __restrict__ logprobs,      // (B*K, V)
    const int*   __restrict__ beam_seq_in,   // (B, K, T)
    const float* __restrict__ bslp_in,       // (B, K, T, V)
    const float* __restrict__ state_in,      // (2, B*K, H)
    u64* __restrict__ srcrow,                // [3360] src addr per out1 row
    u64* __restrict__ srcst,                 // [320]  src addr per state row
    float* __restrict__ out)
{
    const int b   = blockIdx.x;
    const int tid = threadIdx.x;

    float tv[5]; int ti[5];
    if (tid < NSPLIT) {
        const size_t base = ((size_t)b * NSPLIT + tid) * 5;
#pragma unroll
        for (int j = 0; j < 5; ++j) { tv[j] = pv[base + j]; ti[j] = pi[base + j]; }
    } else {
#pragma unroll
        for (int j = 0; j < 5; ++j) { tv[j] = -INFINITY; ti[j] = 0x7FFFFF00 + j; }
    }

    // shuffle-allreduce within the first 16 lanes, then broadcast lane 0
#pragma unroll
    for (int st = 1; st <= 8; st <<= 1) {
        float bv[5]; int bi[5];
#pragma unroll
        for (int j = 0; j < 5; ++j) {
            bv[j] = __shfl_xor(tv[j], st);
            bi[j] = __shfl_xor(ti[j], st);
        }
        merge_sorted5(tv, ti, bv, bi);
    }
#pragma unroll
    for (int j = 0; j < 5; ++j) {
        tv[j] = __shfl(tv[j], 0);
        ti[j] = __shfl(ti[j], 0);
    }
    // every lane now holds the final top-5 for batch b
    int beam[5], sel[5];
#pragma unroll
    for (int j = 0; j < 5; ++j) { beam[j] = ti[j] / VV; sel[j] = ti[j] - beam[j] * VV; }

    // out1 source-row table + beam_seq output (105 rows per batch)
    for (int rr = tid; rr < KK * (TT + 1); rr += 64) {
        const int k = rr / (TT + 1), t = rr % (TT + 1);
        int bm = 0, sl = 0;
#pragma unroll
        for (int j = 0; j < 5; ++j) if (k == j) { bm = beam[j]; sl = sel[j]; }
        const float* src = (t < TT)
            ? bslp_in  + ((size_t)((b * KK + bm) * TT + t)) * VV
            : logprobs + (size_t)(b * KK + bm) * VV;
        srcrow[b * KK * (TT + 1) + rr] = (u64)(uintptr_t)src;
        const int val = (t < TT) ? beam_seq_in[(size_t)(b * KK + bm) * TT + t] : sl;
        out[(size_t)b * KK * (TT + 1) + rr] = (float)val;
    }

    // state source-row table (2 x 5 rows per batch)
    if (tid < 10) {
        const int s = tid / 5, k = tid % 5;
        int bm = 0;
#pragma unroll
        for (int j = 0; j < 5; ++j) if (k == j) bm = beam[j];
        srcst[s * (BB * KK) + b * KK + k] =
            (u64)(uintptr_t)(state_in + ((size_t)s * (BB * KK) + b * KK + bm) * HH);
    }

    // beam_logprobs_sum output
    if (tid == 0) {
#pragma unroll
        for (int j = 0; j < 5; ++j) out[OFF2 + b * KK + j] = tv[j];
    }
}

// ---------------- Phase 3: flat grid-stride float4 copy (round-6 structure) --
// Single change vs round 6: nontemporal stores, so the 129 MB write stream
// does not evict the ~130 MB input set from L3 across graph replays.
__global__ __launch_bounds__(256) void copy_kernel(
    const u64* __restrict__ srcrow,
    const u64* __restrict__ srcst,
    float* __restrict__ out)
{
    f4* __restrict__ dst1 = (f4*)(out + OFF1);
    f4* __restrict__ dst3 = (f4*)(out + OFF3);
    const int stride = gridDim.x * 256;
    for (int idx = blockIdx.x * 256 + threadIdx.x; idx < TOTF4; idx += stride) {
        if (idx < N1F4) {
            const unsigned row = (unsigned)idx / 2372u;
            const unsigned col = (unsigned)idx - row * 2372u;
            const f4* __restrict__ s = (const f4*)(uintptr_t)srcrow[row];
            f4 v = s[col];
            __builtin_nontemporal_store(v, &dst1[idx]);
        } else {
            const int j = idx - N1F4;
            const int r = j >> 8, col = j & 255;
            const f4* __restrict__ s = (const f4*)(uintptr_t)srcst[r];
            f4 v = s[col];
            __builtin_nontemporal_store(v, &dst3[j]);
        }
    }
}

extern "C" void kernel_launch(void* const* d_in, const int* in_sizes, int n_in,
                              void* d_out, int out_size, void* d_ws, size_t ws_size,
                              hipStream_t stream) {
    const float* logprobs = (const float*)d_in[0];
    const int*   beam_seq = (const int*)  d_in[1];
    const float* bslp     = (const float*)d_in[2];
    const float* sums     = (const float*)d_in[3];
    const float* state    = (const float*)d_in[4];

    // ws layout: 8B-aligned tables first, then pv/pi
    u64*   srcrow = (u64*)d_ws;                       // 3360 entries
    u64*   srcst  = srcrow + BB * KK * (TT + 1);      // 320 entries
    float* pv     = (float*)(srcst + 2 * BB * KK);    // 2560 floats
    int*   pi     = (int*)(pv + BB * NSPLIT * 5);     // 2560 ints
    float* out    = (float*)d_out;

    topk_part_kernel<<<BB * NSPLIT, 256, 0, stream>>>(logprobs, sums, pv, pi);
    merge_kernel<<<BB, 64, 0, stream>>>(pv, pi, logprobs, beam_seq, bslp, state,
                                        srcrow, srcst, out);
    copy_kernel<<<2048, 256, 0, stream>>>(srcrow, srcst, out);
}